// Round 6
// baseline (193.348 us; speedup 1.0000x reference)
//
#include <hip/hip_runtime.h>

#define NB 8
#define DM 256
#define FD 96

using half8 = _Float16 __attribute__((ext_vector_type(8)));
using f32x4 = float __attribute__((ext_vector_type(4)));

__device__ __forceinline__ float clamp01(float x) { return fminf(fmaxf(x, 0.0f), 1.0f); }

// ---------------------------------------------------------------------------
// Kernel 0: precompute B = lin_w^T as f16 MFMA fragments into d_ws (48 KB).
// Fragment map (16x16x32): elem j <-> k = 4*(l>>4)+(j&3)+16*(j>>2), col = l&15.
// Layout: frag fb = ks*16+nb, lane l -> half8 at Bpre[(fb*64+l)*8].
// ---------------------------------------------------------------------------
__global__ void bprep_kernel(const float* __restrict__ lin_w,
                             _Float16* __restrict__ Bpre)
{
    const int fb = blockIdx.x * 256 + threadIdx.x;     // 0..3071
    const int ks = fb >> 10, nbv = (fb >> 6) & 15, ll = fb & 63;
    const float* lwrow = lin_w + (size_t)(nbv * 16 + (ll & 15)) * FD
                               + (ks * 32 + 4 * (ll >> 4));
    float4 lo = *reinterpret_cast<const float4*>(lwrow);
    float4 hi = *reinterpret_cast<const float4*>(lwrow + 16);
    half8 v;
    v[0] = (_Float16)lo.x; v[1] = (_Float16)lo.y; v[2] = (_Float16)lo.z; v[3] = (_Float16)lo.w;
    v[4] = (_Float16)hi.x; v[5] = (_Float16)hi.y; v[6] = (_Float16)hi.z; v[7] = (_Float16)hi.w;
    *reinterpret_cast<half8*>(Bpre + (size_t)fb * 8) = v;
}

// ---------------------------------------------------------------------------
// Kernel A: per-position sim (1 thread/pos). h/W written via per-wave LDS
// transpose (32 KB total -> 4 blocks/CU) so every store covers full lines.
// ---------------------------------------------------------------------------
__global__ __launch_bounds__(256, 4) void bio_sim_kernel(
    const int* __restrict__ bits,
    const float* __restrict__ stim_in,
    const float* __restrict__ Winit,
    const int* __restrict__ steps_ptr,
    float* __restrict__ out_h,
    float* __restrict__ out_W,
    int npos)
{
    const int pos = blockIdx.x * blockDim.x + threadIdx.x;
    const int steps = steps_ptr[0];

    float h[NB][4];
    float W[NB][NB];

    const int4* bp = reinterpret_cast<const int4*>(bits + (size_t)pos * 64);
    #pragma unroll
    for (int b = 0; b < NB; ++b) {
        int4 lo = bp[2 * b + 0];
        int4 hi = bp[2 * b + 1];
        h[b][0] = (float)(lo.x * 2 + lo.y) / 3.0f;
        h[b][1] = (float)(lo.z * 2 + lo.w) / 3.0f;
        h[b][2] = (float)(hi.x * 2 + hi.y) / 3.0f;
        h[b][3] = (float)(hi.z * 2 + hi.w) / 3.0f;
    }

    const float4* wp = reinterpret_cast<const float4*>(Winit + (size_t)pos * 64);
    #pragma unroll
    for (int i = 0; i < NB; ++i) {
        float4 a = wp[2 * i + 0];
        float4 b = wp[2 * i + 1];
        W[i][0] = a.x; W[i][1] = a.y; W[i][2] = a.z; W[i][3] = a.w;
        W[i][4] = b.x; W[i][5] = b.y; W[i][6] = b.z; W[i][7] = b.w;
        W[i][i] = 0.0f;
    }

    const float stim = stim_in[pos];

    for (int st = 0; st < steps; ++st) {
        float nb[NB][4];
        #pragma unroll
        for (int i = 0; i < NB; ++i) {
            float s0 = 0.f, s1 = 0.f, s2 = 0.f, s3 = 0.f, tw = 0.f;
            #pragma unroll
            for (int j = 0; j < NB; ++j) {
                float w = W[i][j];
                s0 += w * h[j][0];
                s1 += w * h[j][1];
                s2 += w * h[j][2];
                s3 += w * h[j][3];
                tw += w;
            }
            float inv = 1.0f / (tw + 1e-8f);
            nb[i][0] = s0 * inv; nb[i][1] = s1 * inv;
            nb[i][2] = s2 * inv; nb[i][3] = s3 * inv;
        }
        #pragma unroll
        for (int i = 0; i < NB; ++i) {
            float E = h[i][0], P = h[i][1], G = h[i][2], L = h[i][3];
            float En = nb[i][0], Pn = nb[i][1], Gn = nb[i][2], Ln = nb[i][3];
            float E_new = clamp01(E + 0.3f * stim - 0.4f * P - 0.2f * G);
            float P_new = clamp01(P + 0.5f * stim + 0.3f * (Pn - P) - 0.2f * E);
            float G_new = clamp01(G + 0.4f * E * (1.0f - P) + 0.2f * (Gn - G) - 0.3f * P);
            float good  = 0.5f * En + 0.5f * Gn;
            float L_new = clamp01(L + 0.4f * good + 0.3f * (Ln - L) - 0.3f * P);
            h[i][0] = E_new; h[i][1] = P_new; h[i][2] = G_new; h[i][3] = L_new;
        }
        #pragma unroll
        for (int i = 0; i < NB; ++i) {
            #pragma unroll
            for (int j = i + 1; j < NB; ++j) {
                float d0 = h[i][0] - h[j][0];
                float d1 = h[i][1] - h[j][1];
                float d2 = h[i][2] - h[j][2];
                float d3 = h[i][3] - h[j][3];
                float q = d0 * d0 + d1 * d1 + d2 * d2 + d3 * d3;
                float dist = (q > 0.0f) ? sqrtf(q) : 0.0f;
                float inc = 0.1f * (0.5f * (h[i][3] + h[j][3])) * dist;
                W[i][j] = clamp01(W[i][j] + inc - 0.05f * W[i][j]);
                W[j][i] = clamp01(W[j][i] + inc - 0.05f * W[j][i]);
            }
        }
    }

    // ---- coalesced output via per-wave LDS transpose, 8 KB/wave (32 KB total)
    __shared__ float xpose[4][2048];
    const int w = threadIdx.x >> 6;
    const int l = threadIdx.x & 63;
    float* buf = xpose[w];
    const int waveBase = blockIdx.x * 256 + w * 64;

    // W in two 32-feature chunks; each chunk = 64 pos x 32 feats = 2048 elems
    #pragma unroll
    for (int c = 0; c < 2; ++c) {
        #pragma unroll
        for (int f2 = 0; f2 < 32; ++f2) {
            const int f = c * 32 + f2;
            buf[l * 32 + (f2 ^ (l & 31))] = W[f >> 3][f & 7];
        }
        __syncthreads();
        float* dst = out_W + (size_t)waveBase * 64 + c * 32;
        #pragma unroll
        for (int i = 0; i < 32; ++i) {                       // FIXED: 32 iters (was 16)
            const int p = i * 2 + (l >> 5), f2 = l & 31;     // p covers 0..63
            dst[p * 64 + f2] = buf[p * 32 + (f2 ^ (p & 31))];
        }
        __syncthreads();
    }
    // h (32 feats)
    #pragma unroll
    for (int f = 0; f < 32; ++f)
        buf[l * 32 + (f ^ (l & 31))] = h[f >> 2][f & 3];
    __syncthreads();
    {
        float* dst = out_h + (size_t)waveBase * 32;
        #pragma unroll
        for (int i = 0; i < 32; ++i) {
            const int p = i * 2 + (l >> 5), f = l & 31;
            dst[i * 64 + l] = buf[p * 32 + (f ^ (p & 31))];
        }
    }
}

// ---------------------------------------------------------------------------
// Kernel B: emb = phys @ lin_w^T + lin_b via f16 MFMA.
// M=64/block; wave w owns rows w*16..w*16+15 (1 M-frag) x 16 N-frags.
// A frags: direct per-lane global float4 gathers (L3-hot) + in-reg f32->f16.
// B frags: coalesced half8 loads from precomputed Bpre (L2-resident).
// C: 33 KB padded LDS transpose, flushed in two 128-col chunks, 512B/inst.
// ---------------------------------------------------------------------------
__global__ __launch_bounds__(256, 4) void einsum_mfma_kernel(
    const float* __restrict__ hsrc,
    const float* __restrict__ wsrc,
    const _Float16* __restrict__ Bpre,
    const float* __restrict__ lin_b,
    float* __restrict__ out_emb)
{
    __shared__ float Cbuf[64 * 132];
    const int tid = threadIdx.x;
    const int w = tid >> 6, l = tid & 63;
    const int pos0 = blockIdx.x * 64;

    // A fragments: row = l&15, k = ks*32 + 4*(l>>4) (+0..3, +16..19)
    const int arow = pos0 + w * 16 + (l & 15);
    const int koff = 4 * (l >> 4);
    half8 afr[3];
    {
        const float* s0 = hsrc + (size_t)arow * 32 + koff;
        float4 lo = *reinterpret_cast<const float4*>(s0);
        float4 hi = *reinterpret_cast<const float4*>(s0 + 16);
        afr[0][0] = (_Float16)lo.x; afr[0][1] = (_Float16)lo.y;
        afr[0][2] = (_Float16)lo.z; afr[0][3] = (_Float16)lo.w;
        afr[0][4] = (_Float16)hi.x; afr[0][5] = (_Float16)hi.y;
        afr[0][6] = (_Float16)hi.z; afr[0][7] = (_Float16)hi.w;
        #pragma unroll
        for (int ks = 1; ks < 3; ++ks) {
            const float* s = wsrc + (size_t)arow * 64 + (ks - 1) * 32 + koff;
            float4 a = *reinterpret_cast<const float4*>(s);
            float4 b = *reinterpret_cast<const float4*>(s + 16);
            afr[ks][0] = (_Float16)a.x; afr[ks][1] = (_Float16)a.y;
            afr[ks][2] = (_Float16)a.z; afr[ks][3] = (_Float16)a.w;
            afr[ks][4] = (_Float16)b.x; afr[ks][5] = (_Float16)b.y;
            afr[ks][6] = (_Float16)b.z; afr[ks][7] = (_Float16)b.w;
        }
    }

    // MFMA: acc[nb] over 3 K-steps
    f32x4 acc[16];
    #pragma unroll
    for (int nbv = 0; nbv < 16; ++nbv) acc[nbv] = (f32x4){0.f, 0.f, 0.f, 0.f};
    #pragma unroll
    for (int ks = 0; ks < 3; ++ks) {
        #pragma unroll
        for (int nbv = 0; nbv < 16; ++nbv) {
            half8 b = *reinterpret_cast<const half8*>(Bpre + (size_t)((ks * 16 + nbv) * 64 + l) * 8);
            acc[nbv] = __builtin_amdgcn_mfma_f32_16x16x32_f16(afr[ks], b, acc[nbv], 0, 0, 0);
        }
    }

    // C flush in two 128-col chunks through padded LDS (stride 132)
    #pragma unroll
    for (int c = 0; c < 2; ++c) {
        #pragma unroll
        for (int nn = 0; nn < 8; ++nn) {
            const int nbv = c * 8 + nn;
            #pragma unroll
            for (int r = 0; r < 4; ++r) {
                const int row = w * 16 + 4 * (l >> 4) + r;
                Cbuf[row * 132 + nn * 16 + (l & 15)] = acc[nbv][r];
            }
        }
        __syncthreads();
        const float4 biasv = reinterpret_cast<const float4*>(lin_b)[c * 32 + (l & 31)];
        #pragma unroll
        for (int rep = 0; rep < 8; ++rep) {
            const int row = w * 16 + rep * 2 + (l >> 5);
            float4 v = *reinterpret_cast<const float4*>(Cbuf + row * 132 + (l & 31) * 4);
            v.x += biasv.x; v.y += biasv.y; v.z += biasv.z; v.w += biasv.w;
            *reinterpret_cast<float4*>(out_emb + (size_t)(pos0 + row) * DM + c * 128 + (l & 31) * 4) = v;
        }
        __syncthreads();
    }
}

extern "C" void kernel_launch(void* const* d_in, const int* in_sizes, int n_in,
                              void* d_out, int out_size, void* d_ws, size_t ws_size,
                              hipStream_t stream) {
    const int*   bits  = (const int*)d_in[0];
    const float* stim  = (const float*)d_in[1];
    const float* Winit = (const float*)d_in[2];
    const float* lin_w = (const float*)d_in[3];
    const float* lin_b = (const float*)d_in[4];
    const int*   steps = (const int*)d_in[5];

    const int npos = in_sizes[1];   // B*S = 131072

    float* out_emb = (float*)d_out;
    float* out_h   = out_emb + (size_t)npos * DM;
    float* out_W   = out_h + (size_t)npos * 32;
    _Float16* Bpre = (_Float16*)d_ws;            // 48 KB fragment buffer

    hipLaunchKernelGGL(bprep_kernel, dim3(12), dim3(256), 0, stream, lin_w, Bpre);
    hipLaunchKernelGGL(bio_sim_kernel, dim3(npos / 256), dim3(256), 0, stream,
                       bits, stim, Winit, steps, out_h, out_W, npos);
    hipLaunchKernelGGL(einsum_mfma_kernel, dim3(npos / 64), dim3(256), 0, stream,
                       out_h, out_W, Bpre, lin_b, out_emb);
}

// Round 7
// 119.512 us; speedup vs baseline: 1.6178x; 1.6178x over previous
//
#include <hip/hip_runtime.h>

#define NB 8
#define DM 256
#define FD 96

using half8 = _Float16 __attribute__((ext_vector_type(8)));
using f32x4 = float __attribute__((ext_vector_type(4)));

__device__ __forceinline__ float clamp01(float x) { return fminf(fmaxf(x, 0.0f), 1.0f); }

// ---------------------------------------------------------------------------
// Kernel 0: precompute B = lin_w^T as f16 MFMA fragments into d_ws (48 KB).
// Fragment map (16x16x32): elem j <-> k = 4*(l>>4)+(j&3)+16*(j>>2), col = l&15.
// ---------------------------------------------------------------------------
__global__ void bprep_kernel(const float* __restrict__ lin_w,
                             _Float16* __restrict__ Bpre)
{
    const int fb = blockIdx.x * 256 + threadIdx.x;     // 0..3071
    const int ks = fb >> 10, nbv = (fb >> 6) & 15, ll = fb & 63;
    const float* lwrow = lin_w + (size_t)(nbv * 16 + (ll & 15)) * FD
                               + (ks * 32 + 4 * (ll >> 4));
    float4 lo = *reinterpret_cast<const float4*>(lwrow);
    float4 hi = *reinterpret_cast<const float4*>(lwrow + 16);
    half8 v;
    v[0] = (_Float16)lo.x; v[1] = (_Float16)lo.y; v[2] = (_Float16)lo.z; v[3] = (_Float16)lo.w;
    v[4] = (_Float16)hi.x; v[5] = (_Float16)hi.y; v[6] = (_Float16)hi.z; v[7] = (_Float16)hi.w;
    *reinterpret_cast<half8*>(Bpre + (size_t)fb * 8) = v;
}

// ---------------------------------------------------------------------------
// Kernel A: per-position sim (1 thread/pos). h/W written via per-wave LDS
// transpose (32 KB total). launch_bounds (256,2): (256,4) made the compiler
// cap at 64 VGPRs and spill 96+ floats of state -> 173 MB scratch traffic
// (round-6 counters). (256,2) gives 128 VGPRs, no spill.
// ---------------------------------------------------------------------------
__global__ __launch_bounds__(256, 2) void bio_sim_kernel(
    const int* __restrict__ bits,
    const float* __restrict__ stim_in,
    const float* __restrict__ Winit,
    const int* __restrict__ steps_ptr,
    float* __restrict__ out_h,
    float* __restrict__ out_W,
    int npos)
{
    const int pos = blockIdx.x * blockDim.x + threadIdx.x;
    const int steps = steps_ptr[0];

    float h[NB][4];
    float W[NB][NB];

    const int4* bp = reinterpret_cast<const int4*>(bits + (size_t)pos * 64);
    #pragma unroll
    for (int b = 0; b < NB; ++b) {
        int4 lo = bp[2 * b + 0];
        int4 hi = bp[2 * b + 1];
        h[b][0] = (float)(lo.x * 2 + lo.y) / 3.0f;
        h[b][1] = (float)(lo.z * 2 + lo.w) / 3.0f;
        h[b][2] = (float)(hi.x * 2 + hi.y) / 3.0f;
        h[b][3] = (float)(hi.z * 2 + hi.w) / 3.0f;
    }

    const float4* wp = reinterpret_cast<const float4*>(Winit + (size_t)pos * 64);
    #pragma unroll
    for (int i = 0; i < NB; ++i) {
        float4 a = wp[2 * i + 0];
        float4 b = wp[2 * i + 1];
        W[i][0] = a.x; W[i][1] = a.y; W[i][2] = a.z; W[i][3] = a.w;
        W[i][4] = b.x; W[i][5] = b.y; W[i][6] = b.z; W[i][7] = b.w;
        W[i][i] = 0.0f;
    }

    const float stim = stim_in[pos];

    for (int st = 0; st < steps; ++st) {
        float nb[NB][4];
        #pragma unroll
        for (int i = 0; i < NB; ++i) {
            float s0 = 0.f, s1 = 0.f, s2 = 0.f, s3 = 0.f, tw = 0.f;
            #pragma unroll
            for (int j = 0; j < NB; ++j) {
                float w = W[i][j];
                s0 += w * h[j][0];
                s1 += w * h[j][1];
                s2 += w * h[j][2];
                s3 += w * h[j][3];
                tw += w;
            }
            float inv = 1.0f / (tw + 1e-8f);
            nb[i][0] = s0 * inv; nb[i][1] = s1 * inv;
            nb[i][2] = s2 * inv; nb[i][3] = s3 * inv;
        }
        #pragma unroll
        for (int i = 0; i < NB; ++i) {
            float E = h[i][0], P = h[i][1], G = h[i][2], L = h[i][3];
            float En = nb[i][0], Pn = nb[i][1], Gn = nb[i][2], Ln = nb[i][3];
            float E_new = clamp01(E + 0.3f * stim - 0.4f * P - 0.2f * G);
            float P_new = clamp01(P + 0.5f * stim + 0.3f * (Pn - P) - 0.2f * E);
            float G_new = clamp01(G + 0.4f * E * (1.0f - P) + 0.2f * (Gn - G) - 0.3f * P);
            float good  = 0.5f * En + 0.5f * Gn;
            float L_new = clamp01(L + 0.4f * good + 0.3f * (Ln - L) - 0.3f * P);
            h[i][0] = E_new; h[i][1] = P_new; h[i][2] = G_new; h[i][3] = L_new;
        }
        #pragma unroll
        for (int i = 0; i < NB; ++i) {
            #pragma unroll
            for (int j = i + 1; j < NB; ++j) {
                float d0 = h[i][0] - h[j][0];
                float d1 = h[i][1] - h[j][1];
                float d2 = h[i][2] - h[j][2];
                float d3 = h[i][3] - h[j][3];
                float q = d0 * d0 + d1 * d1 + d2 * d2 + d3 * d3;
                float dist = (q > 0.0f) ? sqrtf(q) : 0.0f;
                float inc = 0.1f * (0.5f * (h[i][3] + h[j][3])) * dist;
                W[i][j] = clamp01(W[i][j] + inc - 0.05f * W[i][j]);
                W[j][i] = clamp01(W[j][i] + inc - 0.05f * W[j][i]);
            }
        }
    }

    // ---- coalesced output via per-wave LDS transpose, 8 KB/wave (32 KB total)
    __shared__ float xpose[4][2048];
    const int w = threadIdx.x >> 6;
    const int l = threadIdx.x & 63;
    float* buf = xpose[w];
    const int waveBase = blockIdx.x * 256 + w * 64;

    // W in two 32-feature chunks; each chunk = 64 pos x 32 feats = 2048 elems
    #pragma unroll
    for (int c = 0; c < 2; ++c) {
        #pragma unroll
        for (int f2 = 0; f2 < 32; ++f2) {
            const int f = c * 32 + f2;
            buf[l * 32 + (f2 ^ (l & 31))] = W[f >> 3][f & 7];
        }
        __syncthreads();
        float* dst = out_W + (size_t)waveBase * 64 + c * 32;
        #pragma unroll
        for (int i = 0; i < 32; ++i) {
            const int p = i * 2 + (l >> 5), f2 = l & 31;
            dst[p * 64 + f2] = buf[p * 32 + (f2 ^ (p & 31))];
        }
        __syncthreads();
    }
    // h (32 feats)
    #pragma unroll
    for (int f = 0; f < 32; ++f)
        buf[l * 32 + (f ^ (l & 31))] = h[f >> 2][f & 3];
    __syncthreads();
    {
        float* dst = out_h + (size_t)waveBase * 32;
        #pragma unroll
        for (int i = 0; i < 32; ++i) {
            const int p = i * 2 + (l >> 5), f = l & 31;
            dst[i * 64 + l] = buf[p * 32 + (f ^ (p & 31))];
        }
    }
}

// ---------------------------------------------------------------------------
// Kernel B: emb = phys @ lin_w^T + lin_b via f16 MFMA.  (unchanged, fast)
// ---------------------------------------------------------------------------
__global__ __launch_bounds__(256, 4) void einsum_mfma_kernel(
    const float* __restrict__ hsrc,
    const float* __restrict__ wsrc,
    const _Float16* __restrict__ Bpre,
    const float* __restrict__ lin_b,
    float* __restrict__ out_emb)
{
    __shared__ float Cbuf[64 * 132];
    const int tid = threadIdx.x;
    const int w = tid >> 6, l = tid & 63;
    const int pos0 = blockIdx.x * 64;

    const int arow = pos0 + w * 16 + (l & 15);
    const int koff = 4 * (l >> 4);
    half8 afr[3];
    {
        const float* s0 = hsrc + (size_t)arow * 32 + koff;
        float4 lo = *reinterpret_cast<const float4*>(s0);
        float4 hi = *reinterpret_cast<const float4*>(s0 + 16);
        afr[0][0] = (_Float16)lo.x; afr[0][1] = (_Float16)lo.y;
        afr[0][2] = (_Float16)lo.z; afr[0][3] = (_Float16)lo.w;
        afr[0][4] = (_Float16)hi.x; afr[0][5] = (_Float16)hi.y;
        afr[0][6] = (_Float16)hi.z; afr[0][7] = (_Float16)hi.w;
        #pragma unroll
        for (int ks = 1; ks < 3; ++ks) {
            const float* s = wsrc + (size_t)arow * 64 + (ks - 1) * 32 + koff;
            float4 a = *reinterpret_cast<const float4*>(s);
            float4 b = *reinterpret_cast<const float4*>(s + 16);
            afr[ks][0] = (_Float16)a.x; afr[ks][1] = (_Float16)a.y;
            afr[ks][2] = (_Float16)a.z; afr[ks][3] = (_Float16)a.w;
            afr[ks][4] = (_Float16)b.x; afr[ks][5] = (_Float16)b.y;
            afr[ks][6] = (_Float16)b.z; afr[ks][7] = (_Float16)b.w;
        }
    }

    f32x4 acc[16];
    #pragma unroll
    for (int nbv = 0; nbv < 16; ++nbv) acc[nbv] = (f32x4){0.f, 0.f, 0.f, 0.f};
    #pragma unroll
    for (int ks = 0; ks < 3; ++ks) {
        #pragma unroll
        for (int nbv = 0; nbv < 16; ++nbv) {
            half8 b = *reinterpret_cast<const half8*>(Bpre + (size_t)((ks * 16 + nbv) * 64 + l) * 8);
            acc[nbv] = __builtin_amdgcn_mfma_f32_16x16x32_f16(afr[ks], b, acc[nbv], 0, 0, 0);
        }
    }

    #pragma unroll
    for (int c = 0; c < 2; ++c) {
        #pragma unroll
        for (int nn = 0; nn < 8; ++nn) {
            const int nbv = c * 8 + nn;
            #pragma unroll
            for (int r = 0; r < 4; ++r) {
                const int row = w * 16 + 4 * (l >> 4) + r;
                Cbuf[row * 132 + nn * 16 + (l & 15)] = acc[nbv][r];
            }
        }
        __syncthreads();
        const float4 biasv = reinterpret_cast<const float4*>(lin_b)[c * 32 + (l & 31)];
        #pragma unroll
        for (int rep = 0; rep < 8; ++rep) {
            const int row = w * 16 + rep * 2 + (l >> 5);
            float4 v = *reinterpret_cast<const float4*>(Cbuf + row * 132 + (l & 31) * 4);
            v.x += biasv.x; v.y += biasv.y; v.z += biasv.z; v.w += biasv.w;
            *reinterpret_cast<float4*>(out_emb + (size_t)(pos0 + row) * DM + c * 128 + (l & 31) * 4) = v;
        }
        __syncthreads();
    }
}

extern "C" void kernel_launch(void* const* d_in, const int* in_sizes, int n_in,
                              void* d_out, int out_size, void* d_ws, size_t ws_size,
                              hipStream_t stream) {
    const int*   bits  = (const int*)d_in[0];
    const float* stim  = (const float*)d_in[1];
    const float* Winit = (const float*)d_in[2];
    const float* lin_w = (const float*)d_in[3];
    const float* lin_b = (const float*)d_in[4];
    const int*   steps = (const int*)d_in[5];

    const int npos = in_sizes[1];   // B*S = 131072

    float* out_emb = (float*)d_out;
    float* out_h   = out_emb + (size_t)npos * DM;
    float* out_W   = out_h + (size_t)npos * 32;
    _Float16* Bpre = (_Float16*)d_ws;            // 48 KB fragment buffer

    hipLaunchKernelGGL(bprep_kernel, dim3(12), dim3(256), 0, stream, lin_w, Bpre);
    hipLaunchKernelGGL(bio_sim_kernel, dim3(npos / 256), dim3(256), 0, stream,
                       bits, stim, Winit, steps, out_h, out_W, npos);
    hipLaunchKernelGGL(einsum_mfma_kernel, dim3(npos / 64), dim3(256), 0, stream,
                       out_h, out_W, Bpre, lin_b, out_emb);
}

// Round 8
// 104.526 us; speedup vs baseline: 1.8498x; 1.1434x over previous
//
#include <hip/hip_runtime.h>

#define NB 8
#define DM 256
#define FD 96

using half8 = _Float16 __attribute__((ext_vector_type(8)));
using f32x4 = float __attribute__((ext_vector_type(4)));

__device__ __forceinline__ float clamp01(float x) { return fminf(fmaxf(x, 0.0f), 1.0f); }

// ---------------------------------------------------------------------------
// Kernel 0: precompute B = lin_w^T as f16 MFMA fragments into d_ws (48 KB).
// Fragment map (16x16x32): elem j <-> k = 4*(l>>4)+(j&3)+16*(j>>2), col = l&15.
// ---------------------------------------------------------------------------
__global__ void bprep_kernel(const float* __restrict__ lin_w,
                             _Float16* __restrict__ Bpre)
{
    const int fb = blockIdx.x * 256 + threadIdx.x;     // 0..3071
    const int ks = fb >> 10, nbv = (fb >> 6) & 15, ll = fb & 63;
    const float* lwrow = lin_w + (size_t)(nbv * 16 + (ll & 15)) * FD
                               + (ks * 32 + 4 * (ll >> 4));
    float4 lo = *reinterpret_cast<const float4*>(lwrow);
    float4 hi = *reinterpret_cast<const float4*>(lwrow + 16);
    half8 v;
    v[0] = (_Float16)lo.x; v[1] = (_Float16)lo.y; v[2] = (_Float16)lo.z; v[3] = (_Float16)lo.w;
    v[4] = (_Float16)hi.x; v[5] = (_Float16)hi.y; v[6] = (_Float16)hi.z; v[7] = (_Float16)hi.w;
    *reinterpret_cast<half8*>(Bpre + (size_t)fb * 8) = v;
}

// ---------------------------------------------------------------------------
// Kernel A: per-position sim (1 thread/pos).
// __launch_bounds__(256, 1): live state (h 32 + W 64 + nb 32 + temps) needs
// ~150+ VGPRs. (256,2)/(256,4) let the compiler pick a tighter occupancy
// bucket and SPILL (round 6: it chose 64 VGPRs under a 128 cap -> 173 MB
// scratch traffic). Grid is 512 blocks = 2 waves/SIMD regardless, so the
// 512-VGPR cap costs nothing.
// ---------------------------------------------------------------------------
__global__ __launch_bounds__(256, 1) void bio_sim_kernel(
    const int* __restrict__ bits,
    const float* __restrict__ stim_in,
    const float* __restrict__ Winit,
    const int* __restrict__ steps_ptr,
    float* __restrict__ out_h,
    float* __restrict__ out_W,
    int npos)
{
    const int pos = blockIdx.x * blockDim.x + threadIdx.x;
    const int steps = steps_ptr[0];

    float h[NB][4];
    float W[NB][NB];

    const int4* bp = reinterpret_cast<const int4*>(bits + (size_t)pos * 64);
    #pragma unroll
    for (int b = 0; b < NB; ++b) {
        int4 lo = bp[2 * b + 0];
        int4 hi = bp[2 * b + 1];
        h[b][0] = (float)(lo.x * 2 + lo.y) / 3.0f;
        h[b][1] = (float)(lo.z * 2 + lo.w) / 3.0f;
        h[b][2] = (float)(hi.x * 2 + hi.y) / 3.0f;
        h[b][3] = (float)(hi.z * 2 + hi.w) / 3.0f;
    }

    const float4* wp = reinterpret_cast<const float4*>(Winit + (size_t)pos * 64);
    #pragma unroll
    for (int i = 0; i < NB; ++i) {
        float4 a = wp[2 * i + 0];
        float4 b = wp[2 * i + 1];
        W[i][0] = a.x; W[i][1] = a.y; W[i][2] = a.z; W[i][3] = a.w;
        W[i][4] = b.x; W[i][5] = b.y; W[i][6] = b.z; W[i][7] = b.w;
        W[i][i] = 0.0f;
    }

    const float stim = stim_in[pos];

    for (int st = 0; st < steps; ++st) {
        float nb[NB][4];
        #pragma unroll
        for (int i = 0; i < NB; ++i) {
            float s0 = 0.f, s1 = 0.f, s2 = 0.f, s3 = 0.f, tw = 0.f;
            #pragma unroll
            for (int j = 0; j < NB; ++j) {
                float w = W[i][j];
                s0 += w * h[j][0];
                s1 += w * h[j][1];
                s2 += w * h[j][2];
                s3 += w * h[j][3];
                tw += w;
            }
            float inv = __builtin_amdgcn_rcpf(tw + 1e-8f);   // ~1ulp, replaces 10-inst div
            nb[i][0] = s0 * inv; nb[i][1] = s1 * inv;
            nb[i][2] = s2 * inv; nb[i][3] = s3 * inv;
        }
        #pragma unroll
        for (int i = 0; i < NB; ++i) {
            float E = h[i][0], P = h[i][1], G = h[i][2], L = h[i][3];
            float En = nb[i][0], Pn = nb[i][1], Gn = nb[i][2], Ln = nb[i][3];
            float E_new = clamp01(E + 0.3f * stim - 0.4f * P - 0.2f * G);
            float P_new = clamp01(P + 0.5f * stim + 0.3f * (Pn - P) - 0.2f * E);
            float G_new = clamp01(G + 0.4f * E * (1.0f - P) + 0.2f * (Gn - G) - 0.3f * P);
            float good  = 0.5f * En + 0.5f * Gn;
            float L_new = clamp01(L + 0.4f * good + 0.3f * (Ln - L) - 0.3f * P);
            h[i][0] = E_new; h[i][1] = P_new; h[i][2] = G_new; h[i][3] = L_new;
        }
        #pragma unroll
        for (int i = 0; i < NB; ++i) {
            #pragma unroll
            for (int j = i + 1; j < NB; ++j) {
                float d0 = h[i][0] - h[j][0];
                float d1 = h[i][1] - h[j][1];
                float d2 = h[i][2] - h[j][2];
                float d3 = h[i][3] - h[j][3];
                float q = d0 * d0 + d1 * d1 + d2 * d2 + d3 * d3;
                float dist = (q > 0.0f) ? __builtin_amdgcn_sqrtf(q) : 0.0f;  // 1 inst
                float inc = 0.1f * (0.5f * (h[i][3] + h[j][3])) * dist;
                W[i][j] = clamp01(W[i][j] + inc - 0.05f * W[i][j]);
                W[j][i] = clamp01(W[j][i] + inc - 0.05f * W[j][i]);
            }
        }
    }

    // ---- coalesced output via per-wave LDS transpose, 8 KB/wave (32 KB total)
    __shared__ float xpose[4][2048];
    const int w = threadIdx.x >> 6;
    const int l = threadIdx.x & 63;
    float* buf = xpose[w];
    const int waveBase = blockIdx.x * 256 + w * 64;

    // W in two 32-feature chunks; each chunk = 64 pos x 32 feats = 2048 elems
    #pragma unroll
    for (int c = 0; c < 2; ++c) {
        #pragma unroll
        for (int f2 = 0; f2 < 32; ++f2) {
            const int f = c * 32 + f2;
            buf[l * 32 + (f2 ^ (l & 31))] = W[f >> 3][f & 7];
        }
        __syncthreads();
        float* dst = out_W + (size_t)waveBase * 64 + c * 32;
        #pragma unroll
        for (int i = 0; i < 32; ++i) {
            const int p = i * 2 + (l >> 5), f2 = l & 31;
            dst[p * 64 + f2] = buf[p * 32 + (f2 ^ (p & 31))];
        }
        __syncthreads();
    }
    // h (32 feats)
    #pragma unroll
    for (int f = 0; f < 32; ++f)
        buf[l * 32 + (f ^ (l & 31))] = h[f >> 2][f & 3];
    __syncthreads();
    {
        float* dst = out_h + (size_t)waveBase * 32;
        #pragma unroll
        for (int i = 0; i < 32; ++i) {
            const int p = i * 2 + (l >> 5), f = l & 31;
            dst[i * 64 + l] = buf[p * 32 + (f ^ (p & 31))];
        }
    }
}

// ---------------------------------------------------------------------------
// Kernel B: emb = phys @ lin_w^T + lin_b via f16 MFMA.  (unchanged, ~26 us)
// ---------------------------------------------------------------------------
__global__ __launch_bounds__(256, 4) void einsum_mfma_kernel(
    const float* __restrict__ hsrc,
    const float* __restrict__ wsrc,
    const _Float16* __restrict__ Bpre,
    const float* __restrict__ lin_b,
    float* __restrict__ out_emb)
{
    __shared__ float Cbuf[64 * 132];
    const int tid = threadIdx.x;
    const int w = tid >> 6, l = tid & 63;
    const int pos0 = blockIdx.x * 64;

    const int arow = pos0 + w * 16 + (l & 15);
    const int koff = 4 * (l >> 4);
    half8 afr[3];
    {
        const float* s0 = hsrc + (size_t)arow * 32 + koff;
        float4 lo = *reinterpret_cast<const float4*>(s0);
        float4 hi = *reinterpret_cast<const float4*>(s0 + 16);
        afr[0][0] = (_Float16)lo.x; afr[0][1] = (_Float16)lo.y;
        afr[0][2] = (_Float16)lo.z; afr[0][3] = (_Float16)lo.w;
        afr[0][4] = (_Float16)hi.x; afr[0][5] = (_Float16)hi.y;
        afr[0][6] = (_Float16)hi.z; afr[0][7] = (_Float16)hi.w;
        #pragma unroll
        for (int ks = 1; ks < 3; ++ks) {
            const float* s = wsrc + (size_t)arow * 64 + (ks - 1) * 32 + koff;
            float4 a = *reinterpret_cast<const float4*>(s);
            float4 b = *reinterpret_cast<const float4*>(s + 16);
            afr[ks][0] = (_Float16)a.x; afr[ks][1] = (_Float16)a.y;
            afr[ks][2] = (_Float16)a.z; afr[ks][3] = (_Float16)a.w;
            afr[ks][4] = (_Float16)b.x; afr[ks][5] = (_Float16)b.y;
            afr[ks][6] = (_Float16)b.z; afr[ks][7] = (_Float16)b.w;
        }
    }

    f32x4 acc[16];
    #pragma unroll
    for (int nbv = 0; nbv < 16; ++nbv) acc[nbv] = (f32x4){0.f, 0.f, 0.f, 0.f};
    #pragma unroll
    for (int ks = 0; ks < 3; ++ks) {
        #pragma unroll
        for (int nbv = 0; nbv < 16; ++nbv) {
            half8 b = *reinterpret_cast<const half8*>(Bpre + (size_t)((ks * 16 + nbv) * 64 + l) * 8);
            acc[nbv] = __builtin_amdgcn_mfma_f32_16x16x32_f16(afr[ks], b, acc[nbv], 0, 0, 0);
        }
    }

    #pragma unroll
    for (int c = 0; c < 2; ++c) {
        #pragma unroll
        for (int nn = 0; nn < 8; ++nn) {
            const int nbv = c * 8 + nn;
            #pragma unroll
            for (int r = 0; r < 4; ++r) {
                const int row = w * 16 + 4 * (l >> 4) + r;
                Cbuf[row * 132 + nn * 16 + (l & 15)] = acc[nbv][r];
            }
        }
        __syncthreads();
        const float4 biasv = reinterpret_cast<const float4*>(lin_b)[c * 32 + (l & 31)];
        #pragma unroll
        for (int rep = 0; rep < 8; ++rep) {
            const int row = w * 16 + rep * 2 + (l >> 5);
            float4 v = *reinterpret_cast<const float4*>(Cbuf + row * 132 + (l & 31) * 4);
            v.x += biasv.x; v.y += biasv.y; v.z += biasv.z; v.w += biasv.w;
            *reinterpret_cast<float4*>(out_emb + (size_t)(pos0 + row) * DM + c * 128 + (l & 31) * 4) = v;
        }
        __syncthreads();
    }
}

extern "C" void kernel_launch(void* const* d_in, const int* in_sizes, int n_in,
                              void* d_out, int out_size, void* d_ws, size_t ws_size,
                              hipStream_t stream) {
    const int*   bits  = (const int*)d_in[0];
    const float* stim  = (const float*)d_in[1];
    const float* Winit = (const float*)d_in[2];
    const float* lin_w = (const float*)d_in[3];
    const float* lin_b = (const float*)d_in[4];
    const int*   steps = (const int*)d_in[5];

    const int npos = in_sizes[1];   // B*S = 131072

    float* out_emb = (float*)d_out;
    float* out_h   = out_emb + (size_t)npos * DM;
    float* out_W   = out_h + (size_t)npos * 32;
    _Float16* Bpre = (_Float16*)d_ws;            // 48 KB fragment buffer

    hipLaunchKernelGGL(bprep_kernel, dim3(12), dim3(256), 0, stream, lin_w, Bpre);
    hipLaunchKernelGGL(bio_sim_kernel, dim3(npos / 256), dim3(256), 0, stream,
                       bits, stim, Winit, steps, out_h, out_W, npos);
    hipLaunchKernelGGL(einsum_mfma_kernel, dim3(npos / 64), dim3(256), 0, stream,
                       out_h, out_W, Bpre, lin_b, out_emb);
}